// Round 9
// baseline (3111.985 us; speedup 1.0000x reference)
//
#include <hip/hip_runtime.h>

// Problem: B=64, T=1024, D=512, F=512, all fp32.
// out[b,t,:] = h_t = tanh(x_t @ W_ih + bias + h_{t-1} @ W_hh)
//
// K1: x_proj GEMM [65536,512]@[512,512]+bias -> d_out (xp buffer, overwritten
//     in-place by the scan; each slot read exactly once before overwrite).
// K2: persistent scan, wave-autonomous (R8 structure) + THIS ROUND: chunked
//     arrival pipeline. R8 post-mortem: post-arrival tail was ~2500cy
//     (sentinel round + separate 8-load verify round + full 512-k FMA all
//     AFTER the last packet, fan-in max-of-16 waves). Split each half-wave's
//     256-k range by producer member: chunk A = member 2ks (k in VGPR wr),
//     chunk B = member 2ks+1 (k in LDS Wl). Per step: poll A -> stage A ->
//     PRE-ISSUE B's 4 loads -> FMA-A (hides B latency) -> check B (usually
//     landed) -> stage B -> FMA-B -> shfl -> tanh -> store. Tail ~900cy,
//     per-chunk fan-in 4 producer waves.
//     W residency (R8-verified, VGPR=200): 128 floats in wr[] + 128 in
//     thread-private LDS slice Wl[tid][132] -> zero W traffic in the loop.
//     Exchange: 8B self-validating packets {lo=val, hi=step tag}, relaxed
//     agent-scope atomics (R2-verified MALL coherence point).
//     ORDERING LEDGER (chunked version -- the subtle part): each wave's poll
//     UNION (ks=0 half: members {0,1}; ks=1: {2,3}) covers ALL 512 row cols,
//     and shfl_xor JOINS both halves before every store. So wave O's
//     overwrite of a parity slot at t+2 <= O's both-half polls@t+2 pass <=
//     every wave of the row stored t+1 <= each wave's shfl forced both its
//     halves' tag-t reads done. Double parity buffer suffices. Stale tags are
//     t-2 or 0xFFFFFFFF -> exact-match never false-positives. Zero barriers
//     (hs half-wave-private, Wl thread-private). Wait graph = DAG over
//     (wave,t); LDS 151KB -> 1 block/CU -> all 256 blocks co-resident -> the
//     spins cannot deadlock.

#define RNN_B 64
#define RNN_T 1024
#define RNN_D 512
#define RNN_F 512

#define HLD(p) __hip_atomic_load((p), __ATOMIC_RELAXED, __HIP_MEMORY_SCOPE_AGENT)

// ---------------------------------------------------------------------------
// Kernel 1: x_proj = X @ W_ih + bias.  M=65536, N=512, K=512.  (unchanged)
// ---------------------------------------------------------------------------
__global__ __launch_bounds__(256) void xproj_gemm(
    const float* __restrict__ A,     // [65536, 512]
    const float* __restrict__ W,     // [512, 512]
    const float* __restrict__ bias,  // [512]
    float* __restrict__ C)           // [65536, 512]
{
    __shared__ float As[16][132];
    __shared__ float Bs[16][132];

    const int tid = threadIdx.x;
    const int bid = blockIdx.x;
    const int mt = bid >> 2;
    const int nt = bid & 3;
    const size_t M0 = (size_t)mt * 128;
    const int N0 = nt * 128;

    const int tm = tid >> 4;
    const int tn = tid & 15;

    const int ar = tid >> 2;
    const int ac = (tid & 3) * 4;
    const int br = tid >> 5;
    const int bc = (tid & 31) * 4;

    float acc[8][8];
    #pragma unroll
    for (int i = 0; i < 8; ++i)
        #pragma unroll
        for (int jx = 0; jx < 8; ++jx) acc[i][jx] = 0.f;

    float bv[8];
    #pragma unroll
    for (int i = 0; i < 8; ++i) bv[i] = bias[N0 + tn * 8 + i];

    for (int k0 = 0; k0 < 512; k0 += 16) {
        float4 a0 = *(const float4*)(A + (M0 + ar) * 512 + k0 + ac);
        float4 a1 = *(const float4*)(A + (M0 + ar + 64) * 512 + k0 + ac);
        float4 b0 = *(const float4*)(W + (size_t)(k0 + br) * 512 + N0 + bc);
        float4 b1 = *(const float4*)(W + (size_t)(k0 + br + 8) * 512 + N0 + bc);
        __syncthreads();
        As[ac + 0][ar] = a0.x; As[ac + 1][ar] = a0.y;
        As[ac + 2][ar] = a0.z; As[ac + 3][ar] = a0.w;
        As[ac + 0][ar + 64] = a1.x; As[ac + 1][ar + 64] = a1.y;
        As[ac + 2][ar + 64] = a1.z; As[ac + 3][ar + 64] = a1.w;
        *(float4*)&Bs[br][bc]     = b0;
        *(float4*)&Bs[br + 8][bc] = b1;
        __syncthreads();
        #pragma unroll
        for (int kk = 0; kk < 16; ++kk) {
            float a[8], bb[8];
            *(float4*)&a[0]  = *(const float4*)&As[kk][tm * 8];
            *(float4*)&a[4]  = *(const float4*)&As[kk][tm * 8 + 4];
            *(float4*)&bb[0] = *(const float4*)&Bs[kk][tn * 8];
            *(float4*)&bb[4] = *(const float4*)&Bs[kk][tn * 8 + 4];
            #pragma unroll
            for (int i = 0; i < 8; ++i)
                #pragma unroll
                for (int jx = 0; jx < 8; ++jx)
                    acc[i][jx] = fmaf(a[i], bb[jx], acc[i][jx]);
        }
    }

    #pragma unroll
    for (int i = 0; i < 8; ++i) {
        float* crow = C + (M0 + tm * 8 + i) * 512 + N0 + tn * 8;
        float4 o0, o1;
        o0.x = acc[i][0] + bv[0]; o0.y = acc[i][1] + bv[1];
        o0.z = acc[i][2] + bv[2]; o0.w = acc[i][3] + bv[3];
        o1.x = acc[i][4] + bv[4]; o1.y = acc[i][5] + bv[5];
        o1.z = acc[i][6] + bv[6]; o1.w = acc[i][7] + bv[7];
        *(float4*)crow = o0;
        *((float4*)crow + 1) = o1;
    }
}

// ---------------------------------------------------------------------------
// Kernel 2: the scan.  1024 wave-units: (row 0..63) x (member 0..3) x (wave 0..3).
// ---------------------------------------------------------------------------
__global__ __launch_bounds__(256, 1) void rnn_scan(
    const float* __restrict__ whh,          // [512, 512]
    float* __restrict__ out,                // [64,1024,512]; xp, overwritten with h
    unsigned long long* __restrict__ hbuf)  // [2][64][512] 8B {val,tag} packets
{
    __shared__ float Wl[256][132];      // per-thread private W-hi slice, 135168 B
    __shared__ float hs[2][4][512];     // per-wave h staging, parity dbuf, 16384 B

    const int tid = threadIdx.x;
    const int w   = tid >> 6;            // wave 0..3
    const int l   = tid & 63;            // lane
    const int ks  = l >> 5;              // k-segment 0/1 (lane halves)
    const int j   = l & 31;              // lane-in-half
    const int c   = (w << 5) + j;        // col within block slice 0..127
    const int row = blockIdx.x & 63;     // group = batch row
    const int m   = blockIdx.x >> 6;     // member 0..3
    const int col = (m << 7) + c;        // output column
    const int hsb = ks << 8;             // this half's k-base in hs (0 or 256)

    // W: k in [256ks, 256ks+128) -> VGPR (chunk A = member 2ks);
    //    k in [256ks+128, 256ks+256) -> LDS (chunk B = member 2ks+1).
    // Wl[tid] written/read ONLY by this thread -> never needs a barrier.
    float wr[128];
    #pragma unroll
    for (int i = 0; i < 128; ++i)
        wr[i] = whh[(size_t)(hsb + i) * RNN_F + col];
    #pragma unroll
    for (int i = 0; i < 128; ++i)
        Wl[tid][i] = whh[(size_t)(hsb + 128 + i) * RNN_F + col];

    float* orow = out + (size_t)row * RNN_T * RNN_F;

    #pragma unroll 1
    for (int t = 0; t < RNN_T; ++t) {
        const int par = t & 1;
        float part;

        if (t > 0) {
            const unsigned tagw = (unsigned)(t - 1);
            // Chunk A: member 2ks, cols 256ks + j + 32i (i=0..3) -- each slot
            // produced by a different wave of that block.
            const unsigned long long* srcA = hbuf +
                (size_t)((t + 1) & 1) * (RNN_B * RNN_F) +
                (size_t)row * RNN_F + (ks << 8) + j;
            const unsigned long long* srcB = srcA + 128;

            // Sentinel spin (1 load; bulk wait at low fabric traffic).
            for (;;) {
                unsigned long long e = HLD(srcA);
                if ((unsigned)(e >> 32) == tagw) break;
            }
            // Verify A: all 4 packets.
            unsigned long long a0, a1, a2, a3;
            for (;;) {
                a0 = HLD(srcA + 0); a1 = HLD(srcA + 32);
                a2 = HLD(srcA + 64); a3 = HLD(srcA + 96);
                unsigned bad = ((unsigned)(a0 >> 32) ^ tagw)
                             | ((unsigned)(a1 >> 32) ^ tagw)
                             | ((unsigned)(a2 >> 32) ^ tagw)
                             | ((unsigned)(a3 >> 32) ^ tagw);
                if (bad == 0u) break;
            }
            // Stage A (half-wave-private slice; same-wave readers only).
            hs[par][w][hsb + j +  0] = __uint_as_float((unsigned)a0);
            hs[par][w][hsb + j + 32] = __uint_as_float((unsigned)a1);
            hs[par][w][hsb + j + 64] = __uint_as_float((unsigned)a2);
            hs[par][w][hsb + j + 96] = __uint_as_float((unsigned)a3);

            // Pre-issue chunk B loads + xp load: latency hides under FMA-A.
            unsigned long long b0 = HLD(srcB + 0), b1 = HLD(srcB + 32);
            unsigned long long b2 = HLD(srcB + 64), b3 = HLD(srcB + 96);
            float xpv = 0.f;
            if (l < 32) xpv = orow[(size_t)t * RNN_F + col];

            // FMA-A: k-lo 128 from VGPR W (broadcast hs reads).
            float f0 = 0.f, f1 = 0.f, f2 = 0.f, f3 = 0.f;
            #pragma unroll
            for (int kk = 0; kk < 128; kk += 4) {
                float4 h4 = *(const float4*)&hs[par][w][hsb + kk];
                f0 = fmaf(h4.x, wr[kk + 0], f0);
                f1 = fmaf(h4.y, wr[kk + 1], f1);
                f2 = fmaf(h4.z, wr[kk + 2], f2);
                f3 = fmaf(h4.w, wr[kk + 3], f3);
            }

            // Verify B (first check uses the pre-issued loads).
            for (;;) {
                unsigned bad = ((unsigned)(b0 >> 32) ^ tagw)
                             | ((unsigned)(b1 >> 32) ^ tagw)
                             | ((unsigned)(b2 >> 32) ^ tagw)
                             | ((unsigned)(b3 >> 32) ^ tagw);
                if (bad == 0u) break;
                b0 = HLD(srcB + 0); b1 = HLD(srcB + 32);
                b2 = HLD(srcB + 64); b3 = HLD(srcB + 96);
            }
            // Stage B.
            hs[par][w][hsb + 128 + j +  0] = __uint_as_float((unsigned)b0);
            hs[par][w][hsb + 128 + j + 32] = __uint_as_float((unsigned)b1);
            hs[par][w][hsb + 128 + j + 64] = __uint_as_float((unsigned)b2);
            hs[par][w][hsb + 128 + j + 96] = __uint_as_float((unsigned)b3);

            // FMA-B: k-hi 128 from LDS W.
            #pragma unroll
            for (int kk = 0; kk < 128; kk += 4) {
                float4 h4 = *(const float4*)&hs[par][w][hsb + 128 + kk];
                float4 w4 = *(const float4*)&Wl[tid][kk];
                f0 = fmaf(h4.x, w4.x, f0);
                f1 = fmaf(h4.y, w4.y, f1);
                f2 = fmaf(h4.z, w4.z, f2);
                f3 = fmaf(h4.w, w4.w, f3);
            }
            part = (f0 + f1) + (f2 + f3);
            part += __shfl_xor(part, 32);   // join ks halves (ledger-critical)

            if (l < 32) {
                float v = tanhf(xpv + part);
                __hip_atomic_store(
                    hbuf + (size_t)par * (RNN_B * RNN_F) + (size_t)row * RNN_F + col,
                    ((unsigned long long)(unsigned)t << 32) | __float_as_uint(v),
                    __ATOMIC_RELAXED, __HIP_MEMORY_SCOPE_AGENT);
                orow[(size_t)t * RNN_F + col] = v;
            }
        } else {
            // t = 0: h_{-1} = 0.
            if (l < 32) {
                float v = tanhf(orow[(size_t)0 * RNN_F + col]);
                __hip_atomic_store(
                    hbuf + (size_t)row * RNN_F + col,
                    __float_as_uint(v),   // tag 0
                    __ATOMIC_RELAXED, __HIP_MEMORY_SCOPE_AGENT);
                orow[(size_t)0 * RNN_F + col] = v;
            }
        }
        // No barriers anywhere: hs half-wave-private (parity dbuf), Wl
        // thread-private, hbuf reuse ordered by the poll-union chain.
    }
}

extern "C" void kernel_launch(void* const* d_in, const int* in_sizes, int n_in,
                              void* d_out, int out_size, void* d_ws, size_t ws_size,
                              hipStream_t stream) {
    const float* X    = (const float*)d_in[0];  // [64,1024,512]
    const float* Wih  = (const float*)d_in[1];  // [512,512]
    const float* Whh  = (const float*)d_in[2];  // [512,512]
    const float* bias = (const float*)d_in[3];  // [512]
    float* out = (float*)d_out;                 // [64,1024,512]

    unsigned long long* hbuf = (unsigned long long*)d_ws;  // 2*64*512*8B = 512 KB

    // Tag field of every packet -> 0xFFFFFFFF (matches no step).
    hipMemsetAsync(hbuf, 0xFF, (size_t)2 * RNN_B * RNN_F * sizeof(unsigned long long),
                   stream);

    xproj_gemm<<<dim3(2048), dim3(256), 0, stream>>>(X, Wih, bias, out);
    rnn_scan<<<dim3(256), dim3(256), 0, stream>>>(Whh, out, hbuf);
}